// Round 4
// baseline (904.412 us; speedup 1.0000x reference)
//
#include <hip/hip_runtime.h>
#include <math.h>

#define RR 64
#define DD 256
#define CAP 6144

// ---------- helpers ----------

__device__ __forceinline__ void get_mu_istd(const double* sums, int N, float& fmu, float& istd) {
  double M = (double)RR * (double)N;
  double mu = sums[0] / M;
  double var = (sums[1] - sums[0] * sums[0] / M) / (M - 1.0);
  fmu = (float)mu;
  istd = (float)(1.0 / sqrt(var));
}

// monotone float<->uint mapping for atomicMax on signed floats
__device__ __forceinline__ unsigned fmap(float f) {
  unsigned b = __float_as_uint(f);
  return (b & 0x80000000u) ? ~b : (b | 0x80000000u);
}
__device__ __forceinline__ float funmap(unsigned u) {
  unsigned b = (u & 0x80000000u) ? (u & 0x7fffffffu) : ~u;
  return __uint_as_float(b);
}

// ---------- K_detect: figure out mask dtype (0=int32, 1=byte, 2=float) ----------

__global__ void k_detect(const unsigned* mask_w, int* flag) {
  __shared__ int f;
  if (threadIdx.x == 0) f = 0;
  __syncthreads();
  int mode = 0;
  for (int i = threadIdx.x; i < 4096; i += 256) {
    unsigned v = mask_w[i];
    if (v == 0x3f800000u) mode = 2;
    else if (v > 1u && mode != 2) mode = 1;
  }
  if (mode) atomicMax(&f, mode);
  __syncthreads();
  if (threadIdx.x == 0) *flag = f;
}

// ---------- K_mask: pack mask into per-column 64-bit words ----------

__global__ __launch_bounds__(256) void k_mask(const void* __restrict__ maskp,
                                              const int* __restrict__ flagp,
                                              unsigned long long* __restrict__ mbits,
                                              int N) {
  int n = blockIdx.x * 256 + threadIdx.x;
  if (n >= N) return;
  const int mode = *flagp;
  unsigned long long b = 0;
  if (mode == 1) {
    const unsigned char* m = (const unsigned char*)maskp;
#pragma unroll
    for (int r = 0; r < RR; ++r)
      b |= (unsigned long long)(m[(size_t)r * N + n] != 0) << r;
  } else if (mode == 2) {
    const float* m = (const float*)maskp;
#pragma unroll
    for (int r = 0; r < RR; ++r)
      b |= (unsigned long long)(m[(size_t)r * N + n] != 0.f) << r;
  } else {
    const int* m = (const int*)maskp;
#pragma unroll
    for (int r = 0; r < RR; ++r)
      b |= (unsigned long long)(m[(size_t)r * N + n] != 0) << r;
  }
  mbits[n] = b;
}

// ---------- K1: hsW = hs @ W   [64 x 256] ----------

__global__ __launch_bounds__(256) void k_hsw(const float* __restrict__ hs,
                                             const float* __restrict__ W,
                                             float* __restrict__ hsW) {
  int i = blockIdx.x;
  int j = threadIdx.x;
  float acc = 0.f;
  for (int k = 0; k < DD; ++k) acc = fmaf(hs[i * DD + k], W[k * DD + j], acc);
  hsW[i * DD + j] = acc;
}

// ---------- K2: scores GEMM, 16 rows x 4 cols per thread ----------
// Thread's 4 cols are {lane, lane+64, lane+128, lane+192} within the block's
// 256-col tile: LDS fragment reads at (lane+64c)*36+k have bank step
// 4*lane mod 32 -> balanced 8 accesses/bank (round-3's lane*4 mapping put all
// 64 lanes on 8 banks -> 9.6M conflict cycles).

__global__ __launch_bounds__(256) void k_scores(const float* __restrict__ es,
                                                const float* __restrict__ hsW,
                                                const unsigned long long* __restrict__ mbits,
                                                float* __restrict__ scores,
                                                float* __restrict__ colmax,
                                                int* __restrict__ colargmax,
                                                double* __restrict__ sums,
                                                unsigned* __restrict__ rowmax_u,
                                                int N) {
  __shared__ float lds[256 * 36];   // es tile [col][36]; reused as stat buffer
  __shared__ double red[8];
  const int tid = threadIdx.x;
  const int lane = tid & 63;
  const int ty = __builtin_amdgcn_readfirstlane(tid >> 6);
  const int n0 = blockIdx.x * 256;
  const int R0 = ty * 16;
  const int nb = n0 + lane;    // col c -> nb + 64*c

  float4 acc[16];
#pragma unroll
  for (int i = 0; i < 16; ++i) acc[i] = make_float4(0.f, 0.f, 0.f, 0.f);

  for (int kc = 0; kc < DD; kc += 32) {
    __syncthreads();
#pragma unroll
    for (int p = 0; p < 8; ++p) {
      int c = p * 32 + (tid >> 3);
      int rr = min(n0 + c, N - 1);
      const float4 v = *(const float4*)(es + (size_t)rr * DD + kc + (tid & 7) * 4);
      *(float4*)(lds + c * 36 + (tid & 7) * 4) = v;
    }
    __syncthreads();
#pragma unroll
    for (int k = 0; k < 32; k += 4) {
      const float4 e0 = *(const float4*)(lds + (lane +   0) * 36 + k);
      const float4 e1 = *(const float4*)(lds + (lane +  64) * 36 + k);
      const float4 e2 = *(const float4*)(lds + (lane + 128) * 36 + k);
      const float4 e3 = *(const float4*)(lds + (lane + 192) * 36 + k);
#pragma unroll
      for (int i = 0; i < 16; ++i) {
        const float4 w = *(const float4*)(hsW + (R0 + i) * DD + kc + k);  // SGPR-uniform
        acc[i].x = fmaf(w.x, e0.x, fmaf(w.y, e0.y, fmaf(w.z, e0.z, fmaf(w.w, e0.w, acc[i].x))));
        acc[i].y = fmaf(w.x, e1.x, fmaf(w.y, e1.y, fmaf(w.z, e1.z, fmaf(w.w, e1.w, acc[i].y))));
        acc[i].z = fmaf(w.x, e2.x, fmaf(w.y, e2.y, fmaf(w.z, e2.z, fmaf(w.w, e2.w, acc[i].z))));
        acc[i].w = fmaf(w.x, e3.x, fmaf(w.y, e3.y, fmaf(w.z, e3.z, fmaf(w.w, e3.w, acc[i].w))));
      }
    }
  }

  // ---- col validity ----
  bool val[4];
#pragma unroll
  for (int c = 0; c < 4; ++c) val[c] = (nb + 64 * c) < N;

  // ---- store scores (4 coalesced dword streams per row) ----
#pragma unroll
  for (int i = 0; i < 16; ++i) {
    float* dst = scores + (size_t)(R0 + i) * N + nb;
    float v[4] = {acc[i].x, acc[i].y, acc[i].z, acc[i].w};
#pragma unroll
    for (int c = 0; c < 4; ++c)
      if (val[c]) dst[64 * c] = v[c];
  }

  // ---- mask bits for my 4 cols ----
  unsigned long long mb[4];
#pragma unroll
  for (int c = 0; c < 4; ++c) mb[c] = val[c] ? mbits[nb + 64 * c] : 0ull;

  // ---- per-col partials over my 16 rows + fused row-max reductions ----
  float ps1[4], ps2[4], pcm[4], pbv[4];
  int pbr[4];
#pragma unroll
  for (int c = 0; c < 4; ++c) { ps1[c] = 0.f; ps2[c] = 0.f; pcm[c] = -INFINITY; pbv[c] = -INFINITY; pbr[c] = -1; }

#pragma unroll
  for (int i = 0; i < 16; ++i) {
    const int rrow = R0 + i;
    float v[4] = {acc[i].x, acc[i].y, acc[i].z, acc[i].w};
    float q = -INFINITY, qm = -INFINITY;
#pragma unroll
    for (int c = 0; c < 4; ++c) {
      ps1[c] += v[c];
      ps2[c] = fmaf(v[c], v[c], ps2[c]);
      pcm[c] = fmaxf(pcm[c], v[c]);
      bool bit = (mb[c] >> rrow) & 1ull;
      if (bit && (v[c] > pbv[c])) { pbv[c] = v[c]; pbr[c] = rrow; }
      float qv = val[c] ? v[c] : -INFINITY;
      q = fmaxf(q, qv);
      if (bit) qm = fmaxf(qm, qv);
    }
#pragma unroll
    for (int o = 32; o > 0; o >>= 1) {
      q = fmaxf(q, __shfl_down(q, o));
      qm = fmaxf(qm, __shfl_down(qm, o));
    }
    if (lane == 0) {
      atomicMax(rowmax_u + rrow, fmap(q));
      atomicMax(rowmax_u + 64 + rrow, fmap(qm));
    }
  }

  // ---- cross-wave col-stat combine via LDS ----
  __syncthreads();   // done with es tile
  float* Ls1 = lds;
  float* Ls2 = lds + 1024;
  float* Lcm = lds + 2048;
  float* Lbv = lds + 3072;
  int* Lbr = (int*)(lds + 4096);
#pragma unroll
  for (int c = 0; c < 4; ++c) {
    int col = lane + 64 * c;
    Ls1[ty * 256 + col] = ps1[c];
    Ls2[ty * 256 + col] = ps2[c];
    Lcm[ty * 256 + col] = pcm[c];
    Lbv[ty * 256 + col] = pbv[c];
    Lbr[ty * 256 + col] = pbr[c];
  }
  __syncthreads();

  const int n = n0 + tid;
  float s1 = 0.f, s2 = 0.f;
  if (n < N) {
    s1 = Ls1[tid] + Ls1[256 + tid] + Ls1[512 + tid] + Ls1[768 + tid];
    s2 = Ls2[tid] + Ls2[256 + tid] + Ls2[512 + tid] + Ls2[768 + tid];
    float cm = fmaxf(fmaxf(Lcm[tid], Lcm[256 + tid]), fmaxf(Lcm[512 + tid], Lcm[768 + tid]));
    colmax[n] = cm;
    float bv = -INFINITY;
    int br = -1;
#pragma unroll
    for (int w2 = 0; w2 < 4; ++w2) {
      float b = Lbv[w2 * 256 + tid];
      if (b > bv) { bv = b; br = Lbr[w2 * 256 + tid]; }
    }
    colargmax[n] = br;
  }

  double d1 = (double)s1, d2 = (double)s2;
#pragma unroll
  for (int o = 32; o > 0; o >>= 1) {
    d1 += __shfl_down(d1, o);
    d2 += __shfl_down(d2, o);
  }
  if ((tid & 63) == 0) { red[ty * 2] = d1; red[ty * 2 + 1] = d2; }
  __syncthreads();
  if (tid == 0) {
    atomicAdd(&sums[0], red[0] + red[2] + red[4] + red[6]);
    atomicAdd(&sums[1], red[1] + red[3] + red[5] + red[7]);
  }
}

// ---------- K3a: per-row plain exp-sums (row maxes already known) ----------

__global__ __launch_bounds__(256) void k_rowsum(const float* __restrict__ scores,
                                                const unsigned long long* __restrict__ mbits,
                                                const double* __restrict__ sums,
                                                const unsigned* __restrict__ rowmax_u,
                                                float* __restrict__ rowpart,
                                                int N) {
  int r = blockIdx.x, sl = blockIdx.y, tid = threadIdx.x;
  float fmu, istd;
  get_mu_istd(sums, N, fmu, istd);
  const float rm = funmap(rowmax_u[r]);
  const float rmm = funmap(rowmax_u[64 + r]);
  int chunk = (N + 7) / 8;
  int nlo = sl * chunk, nhi = min(N, nlo + chunk);

  float lu = 0.f, lm = 0.f;
  for (int n = nlo + tid; n < nhi; n += 256) {
    float x = scores[(size_t)r * N + n];
    lu += expf((x - rm) * istd);
    float bit = (float)((mbits[n] >> r) & 1ull);
    lm = fmaf(bit, expf((x - rmm) * istd), lm);
  }

  __shared__ float red[8];
#pragma unroll
  for (int o = 32; o > 0; o >>= 1) {
    lu += __shfl_down(lu, o);
    lm += __shfl_down(lm, o);
  }
  if ((tid & 63) == 0) { red[(tid >> 6) * 2] = lu; red[(tid >> 6) * 2 + 1] = lm; }
  __syncthreads();
  if (tid == 0) {
    rowpart[((size_t)r * 8 + sl) * 2] = red[0] + red[2] + red[4] + red[6];
    rowpart[((size_t)r * 8 + sl) * 2 + 1] = red[1] + red[3] + red[5] + red[7];
  }
}

// ---------- K3b: finalize row stats ----------

__global__ void k_rowfin(const float* __restrict__ rowpart,
                         const unsigned* __restrict__ rowmax_u,
                         float* __restrict__ rowstats) {
  int r = threadIdx.x;  // 64
  float lu = 0.f, lm = 0.f;
  for (int s = 0; s < 8; ++s) {
    lu += rowpart[((size_t)r * 8 + s) * 2];
    lm += rowpart[((size_t)r * 8 + s) * 2 + 1];
  }
  rowstats[r] = funmap(rowmax_u[r]);
  rowstats[64 + r] = logf(lu);
  rowstats[128 + r] = funmap(rowmax_u[64 + r]);
  rowstats[192 + r] = lm;
}

// ---------- K4: column lse + candidate scatter ----------

__global__ __launch_bounds__(256) void k_colstats(const float* __restrict__ scores,
                                                  const float* __restrict__ colmax,
                                                  const int* __restrict__ colargmax,
                                                  const double* __restrict__ sums,
                                                  const float* __restrict__ rowstats,
                                                  float* __restrict__ collse,
                                                  int* __restrict__ cnt,
                                                  float* __restrict__ candp,
                                                  int* __restrict__ candn,
                                                  int N) {
  __shared__ int lcnt[64], lbase[64];
  int tid = threadIdx.x;
  if (tid < 64) lcnt[tid] = 0;
  __syncthreads();
  int n = blockIdx.x * 256 + tid;
  int br = -1, lpos = 0;
  float prob = 0.f;
  if (n < N) {
    float fmu, istd;
    get_mu_istd(sums, N, fmu, istd);
    float cm = colmax[n];
    br = colargmax[n];
    float sum = 0.f;
    float xbr = 0.f;
#pragma unroll
    for (int r2 = 0; r2 < RR; ++r2) {
      float x = scores[(size_t)r2 * N + n];
      if (r2 == br) xbr = x;
      sum += expf((x - cm) * istd);
    }
    collse[n] = logf(sum);
    if (br >= 0) {
      prob = fmaxf(expf((xbr - rowstats[128 + br]) * istd) / rowstats[192 + br], 1e-6f);
      lpos = atomicAdd(&lcnt[br], 1);
    }
  }
  __syncthreads();
  if (tid < 64) {
    int c = lcnt[tid];
    lbase[tid] = c ? atomicAdd(&cnt[tid], c) : 0;
  }
  __syncthreads();
  if (br >= 0) {
    int pos = lbase[br] + lpos;
    if (pos < CAP) {
      candp[(size_t)br * CAP + pos] = prob;
      candn[(size_t)br * CAP + pos] = n;
    }
  }
}

// ---------- K5: per-row top-50 (prob desc, index asc), 512 threads ----------

__global__ __launch_bounds__(512) void k_topk(const int* __restrict__ cnt,
                                              const float* __restrict__ candp,
                                              const int* __restrict__ candn,
                                              float* __restrict__ out,
                                              int* __restrict__ seln,
                                              int NO) {
  int r = blockIdx.x, tid = threadIdx.x;
  __shared__ float sp[CAP];
  __shared__ int sn[CAP];
  __shared__ float wp[8];
  __shared__ int wn[8], wi[8];
  int c = min(cnt[r], CAP);
  for (int i = tid; i < c; i += 512) {
    sp[i] = candp[(size_t)r * CAP + i];
    sn[i] = candn[(size_t)r * CAP + i];
  }
  __syncthreads();
  for (int j = 0; j < NO; ++j) {
    float bp = -1.f;
    int bn = 0x7fffffff, bi = -1;
    for (int i = tid; i < c; i += 512) {
      float p = sp[i];
      int nn = sn[i];
      if (p > bp || (p == bp && nn < bn)) { bp = p; bn = nn; bi = i; }
    }
#pragma unroll
    for (int o = 32; o > 0; o >>= 1) {
      float p2 = __shfl_down(bp, o);
      int n2 = __shfl_down(bn, o);
      int i2 = __shfl_down(bi, o);
      if (p2 > bp || (p2 == bp && n2 < bn)) { bp = p2; bn = n2; bi = i2; }
    }
    if ((tid & 63) == 0) { wp[tid >> 6] = bp; wn[tid >> 6] = bn; wi[tid >> 6] = bi; }
    __syncthreads();
    if (tid == 0) {
      float fp2 = wp[0]; int fn2 = wn[0], fi2 = wi[0];
#pragma unroll
      for (int w2 = 1; w2 < 8; ++w2) {
        if (wp[w2] > fp2 || (wp[w2] == fp2 && wn[w2] < fn2)) { fp2 = wp[w2]; fn2 = wn[w2]; fi2 = wi[w2]; }
      }
      if (fp2 > 0.f) {
        out[r * NO + j] = (float)fn2;
        seln[r * NO + j] = fn2;
        sp[fi2] = -1.f;
      } else {
        out[r * NO + j] = -1.f;
        seln[r * NO + j] = -1;
      }
    }
    __syncthreads();
  }
}

// ---------- K6: exp_scores ----------

__global__ void k_expand(const float* __restrict__ scores,
                         const double* __restrict__ sums,
                         const float* __restrict__ rowstats,
                         const float* __restrict__ colmax,
                         const float* __restrict__ collse,
                         const int* __restrict__ seln,
                         float* __restrict__ out,
                         int N, int NO) {
  int b = blockIdx.x;
  int r2 = threadIdx.x;
  int n = seln[b];
  float v = 0.f;
  if (n >= 0) {
    float fmu, istd;
    get_mu_istd(sums, N, fmu, istd);
    float x = scores[(size_t)r2 * N + n];
    float v1 = (x - rowstats[r2]) * istd - rowstats[64 + r2];
    float v2 = (x - colmax[n]) * istd - collse[n];
    v = v1 + v2;
  }
  out[RR * NO + (size_t)b * RR + r2] = v;
}

// ---------- launch ----------

extern "C" void kernel_launch(void* const* d_in, const int* in_sizes, int n_in,
                              void* d_out, int out_size, void* d_ws, size_t ws_size,
                              hipStream_t stream) {
  const float* hs = (const float*)d_in[0];
  const float* es = (const float*)d_in[1];
  const float* W = (const float*)d_in[2];
  const void* mask = d_in[3];

  const int N = in_sizes[1] / DD;               // 200000
  const int NO = out_size / (RR * (1 + RR));    // 50

  char* ws = (char*)d_ws;
  size_t o = 0;
  float* scores = (float*)(ws + o);   o += (size_t)RR * N * 4;
  float* hsW = (float*)(ws + o);      o += RR * DD * 4;
  o = (o + 255) & ~(size_t)255;
  double* sums = (double*)(ws + o);
  int* cnt = (int*)(ws + o + 16);
  unsigned* rowmax_u = (unsigned*)(ws + o + 16 + 256);
  size_t zero_off = o, zero_bytes = 16 + 256 + 512;
  o += 1024;
  float* rowstats = (float*)(ws + o); o += 256 * 4;
  float* rowpart = (float*)(ws + o);  o += 64 * 8 * 2 * 4;
  o = (o + 255) & ~(size_t)255;
  float* colmax = (float*)(ws + o);   o += (size_t)N * 4;
  int* colargmax = (int*)(ws + o);    o += (size_t)N * 4;
  float* collse = (float*)(ws + o);   o += (size_t)N * 4;
  o = (o + 255) & ~(size_t)255;
  unsigned long long* mbits = (unsigned long long*)(ws + o); o += (size_t)N * 8;
  o = (o + 255) & ~(size_t)255;
  float* candp = (float*)(ws + o);    o += (size_t)RR * CAP * 4;
  int* candn = (int*)(ws + o);        o += (size_t)RR * CAP * 4;
  int* seln = (int*)(ws + o);         o += (size_t)RR * NO * 4;
  int* flag = (int*)(ws + o);         o += 256;

  hipMemsetAsync(ws + zero_off, 0, zero_bytes, stream);

  const int NB = (N + 255) / 256;

  k_detect<<<1, 256, 0, stream>>>((const unsigned*)mask, flag);
  k_mask<<<NB, 256, 0, stream>>>(mask, flag, mbits, N);
  k_hsw<<<RR, 256, 0, stream>>>(hs, W, hsW);
  k_scores<<<NB, 256, 0, stream>>>(es, hsW, mbits, scores, colmax, colargmax, sums,
                                   rowmax_u, N);
  k_rowsum<<<dim3(RR, 8), 256, 0, stream>>>(scores, mbits, sums, rowmax_u, rowpart, N);
  k_rowfin<<<1, 64, 0, stream>>>(rowpart, rowmax_u, rowstats);
  k_colstats<<<NB, 256, 0, stream>>>(scores, colmax, colargmax, sums, rowstats, collse,
                                     cnt, candp, candn, N);
  k_topk<<<RR, 512, 0, stream>>>(cnt, candp, candn, (float*)d_out, seln, NO);
  k_expand<<<RR * NO, 64, 0, stream>>>(scores, sums, rowstats, colmax, collse, seln,
                                       (float*)d_out, N, NO);
}

// Round 5
// 795.097 us; speedup vs baseline: 1.1375x; 1.1375x over previous
//
#include <hip/hip_runtime.h>
#include <math.h>

#define RR 64
#define DD 256
#define CAP 6144

// ---------- helpers ----------

__device__ __forceinline__ void get_mu_istd(const double* sums, int N, float& fmu, float& istd) {
  double M = (double)RR * (double)N;
  double mu = sums[0] / M;
  double var = (sums[1] - sums[0] * sums[0] / M) / (M - 1.0);
  fmu = (float)mu;
  istd = (float)(1.0 / sqrt(var));
}

// monotone float<->uint mapping for atomicMax on signed floats
__device__ __forceinline__ unsigned fmap(float f) {
  unsigned b = __float_as_uint(f);
  return (b & 0x80000000u) ? ~b : (b | 0x80000000u);
}
__device__ __forceinline__ float funmap(unsigned u) {
  unsigned b = (u & 0x80000000u) ? (u & 0x7fffffffu) : ~u;
  return __uint_as_float(b);
}

// ---------- K_mask: per-block dtype sniff (same 4KB window -> consistent) + pack ----------

__global__ __launch_bounds__(256) void k_mask(const void* __restrict__ maskp,
                                              unsigned long long* __restrict__ mbits,
                                              int N) {
  __shared__ int f;
  int tid = threadIdx.x;
  if (tid == 0) f = 0;
  __syncthreads();
  {
    const unsigned* mw = (const unsigned*)maskp;
    int mode = 0;
    for (int i = tid; i < 4096; i += 256) {
      unsigned v = mw[i];
      if (v == 0x3f800000u) mode = 2;
      else if (v > 1u && mode != 2) mode = 1;
    }
    if (mode) atomicMax(&f, mode);
  }
  __syncthreads();
  const int mode = f;

  int n = blockIdx.x * 256 + tid;
  if (n >= N) return;
  unsigned long long b = 0;
  if (mode == 1) {
    const unsigned char* m = (const unsigned char*)maskp;
#pragma unroll
    for (int r = 0; r < RR; ++r)
      b |= (unsigned long long)(m[(size_t)r * N + n] != 0) << r;
  } else if (mode == 2) {
    const float* m = (const float*)maskp;
#pragma unroll
    for (int r = 0; r < RR; ++r)
      b |= (unsigned long long)(m[(size_t)r * N + n] != 0.f) << r;
  } else {
    const int* m = (const int*)maskp;
#pragma unroll
    for (int r = 0; r < RR; ++r)
      b |= (unsigned long long)(m[(size_t)r * N + n] != 0) << r;
  }
  mbits[n] = b;
}

// ---------- K1: hsW = hs @ W   [64 x 256] ----------

__global__ __launch_bounds__(256) void k_hsw(const float* __restrict__ hs,
                                             const float* __restrict__ W,
                                             float* __restrict__ hsW) {
  int i = blockIdx.x;
  int j = threadIdx.x;
  float acc = 0.f;
  for (int k = 0; k < DD; ++k) acc = fmaf(hs[i * DD + k], W[k * DD + j], acc);
  hsW[i * DD + j] = acc;
}

// ---------- K2: scores GEMM ----------
// Round-5 change: hsW chunk staged in LDS, read via wave-uniform ds_read_b128
// (broadcast, in-order lgkmcnt) -- removes the 16 s_load_dwordx4 + full
// lgkmcnt(0) drains per k4-step that stalled rounds 2-4 (VALUBusy 13-33%,
// wall ~10x the VALU issue time).

__global__ __launch_bounds__(256) void k_scores(const float* __restrict__ es,
                                                const float* __restrict__ hsW,
                                                const unsigned long long* __restrict__ mbits,
                                                float* __restrict__ scores,
                                                float* __restrict__ colmax,
                                                int* __restrict__ colargmax,
                                                double* __restrict__ sums,
                                                unsigned* __restrict__ rowmax_u,
                                                int N) {
  __shared__ float lds[256 * 36];   // es tile [col][36]; reused as stat buffer
  __shared__ float wlds[64 * 32];   // hsW chunk [row][32]
  __shared__ double red[8];
  const int tid = threadIdx.x;
  const int lane = tid & 63;
  const int ty = __builtin_amdgcn_readfirstlane(tid >> 6);
  const int n0 = blockIdx.x * 256;
  const int R0 = ty * 16;
  const int nb = n0 + lane;    // col c -> nb + 64*c

  float4 acc[16];
#pragma unroll
  for (int i = 0; i < 16; ++i) acc[i] = make_float4(0.f, 0.f, 0.f, 0.f);

  for (int kc = 0; kc < DD; kc += 32) {
    __syncthreads();
    // stage es tile (32 KB)
#pragma unroll
    for (int p = 0; p < 8; ++p) {
      int c = p * 32 + (tid >> 3);
      int rr = min(n0 + c, N - 1);
      const float4 v = *(const float4*)(es + (size_t)rr * DD + kc + (tid & 7) * 4);
      *(float4*)(lds + c * 36 + (tid & 7) * 4) = v;
    }
    // stage hsW chunk (8 KB): thread -> row tid/4, k' (tid%4)*8 .. +8
    {
      int wrow = tid >> 2;
      int wk = (tid & 3) * 8;
      const float4 a = *(const float4*)(hsW + wrow * DD + kc + wk);
      const float4 b = *(const float4*)(hsW + wrow * DD + kc + wk + 4);
      *(float4*)(wlds + wrow * 32 + wk) = a;
      *(float4*)(wlds + wrow * 32 + wk + 4) = b;
    }
    __syncthreads();
#pragma unroll
    for (int k = 0; k < 32; k += 4) {
      const float4 e0 = *(const float4*)(lds + (lane +   0) * 36 + k);
      const float4 e1 = *(const float4*)(lds + (lane +  64) * 36 + k);
      const float4 e2 = *(const float4*)(lds + (lane + 128) * 36 + k);
      const float4 e3 = *(const float4*)(lds + (lane + 192) * 36 + k);
#pragma unroll
      for (int i = 0; i < 16; ++i) {
        const float4 w = *(const float4*)(wlds + (R0 + i) * 32 + k);  // uniform -> broadcast
        acc[i].x = fmaf(w.x, e0.x, fmaf(w.y, e0.y, fmaf(w.z, e0.z, fmaf(w.w, e0.w, acc[i].x))));
        acc[i].y = fmaf(w.x, e1.x, fmaf(w.y, e1.y, fmaf(w.z, e1.z, fmaf(w.w, e1.w, acc[i].y))));
        acc[i].z = fmaf(w.x, e2.x, fmaf(w.y, e2.y, fmaf(w.z, e2.z, fmaf(w.w, e2.w, acc[i].z))));
        acc[i].w = fmaf(w.x, e3.x, fmaf(w.y, e3.y, fmaf(w.z, e3.z, fmaf(w.w, e3.w, acc[i].w))));
      }
    }
  }

  // ---- col validity ----
  bool val[4];
#pragma unroll
  for (int c = 0; c < 4; ++c) val[c] = (nb + 64 * c) < N;

  // ---- store scores ----
#pragma unroll
  for (int i = 0; i < 16; ++i) {
    float* dst = scores + (size_t)(R0 + i) * N + nb;
    float v[4] = {acc[i].x, acc[i].y, acc[i].z, acc[i].w};
#pragma unroll
    for (int c = 0; c < 4; ++c)
      if (val[c]) dst[64 * c] = v[c];
  }

  // ---- mask bits for my 4 cols ----
  unsigned long long mb[4];
#pragma unroll
  for (int c = 0; c < 4; ++c) mb[c] = val[c] ? mbits[nb + 64 * c] : 0ull;

  // ---- per-col partials over my 16 rows + fused row-max reductions ----
  float ps1[4], ps2[4], pcm[4], pbv[4];
  int pbr[4];
#pragma unroll
  for (int c = 0; c < 4; ++c) { ps1[c] = 0.f; ps2[c] = 0.f; pcm[c] = -INFINITY; pbv[c] = -INFINITY; pbr[c] = -1; }

#pragma unroll
  for (int i = 0; i < 16; ++i) {
    const int rrow = R0 + i;
    float v[4] = {acc[i].x, acc[i].y, acc[i].z, acc[i].w};
    float q = -INFINITY, qm = -INFINITY;
#pragma unroll
    for (int c = 0; c < 4; ++c) {
      ps1[c] += v[c];
      ps2[c] = fmaf(v[c], v[c], ps2[c]);
      pcm[c] = fmaxf(pcm[c], v[c]);
      bool bit = (mb[c] >> rrow) & 1ull;
      if (bit && (v[c] > pbv[c])) { pbv[c] = v[c]; pbr[c] = rrow; }
      float qv = val[c] ? v[c] : -INFINITY;
      q = fmaxf(q, qv);
      if (bit) qm = fmaxf(qm, qv);
    }
#pragma unroll
    for (int o = 32; o > 0; o >>= 1) {
      q = fmaxf(q, __shfl_down(q, o));
      qm = fmaxf(qm, __shfl_down(qm, o));
    }
    if (lane == 0) {
      atomicMax(rowmax_u + rrow, fmap(q));
      atomicMax(rowmax_u + 64 + rrow, fmap(qm));
    }
  }

  // ---- cross-wave col-stat combine via LDS ----
  __syncthreads();   // done with es tile
  float* Ls1 = lds;
  float* Ls2 = lds + 1024;
  float* Lcm = lds + 2048;
  float* Lbv = lds + 3072;
  int* Lbr = (int*)(lds + 4096);
#pragma unroll
  for (int c = 0; c < 4; ++c) {
    int col = lane + 64 * c;
    Ls1[ty * 256 + col] = ps1[c];
    Ls2[ty * 256 + col] = ps2[c];
    Lcm[ty * 256 + col] = pcm[c];
    Lbv[ty * 256 + col] = pbv[c];
    Lbr[ty * 256 + col] = pbr[c];
  }
  __syncthreads();

  const int n = n0 + tid;
  float s1 = 0.f, s2 = 0.f;
  if (n < N) {
    s1 = Ls1[tid] + Ls1[256 + tid] + Ls1[512 + tid] + Ls1[768 + tid];
    s2 = Ls2[tid] + Ls2[256 + tid] + Ls2[512 + tid] + Ls2[768 + tid];
    float cm = fmaxf(fmaxf(Lcm[tid], Lcm[256 + tid]), fmaxf(Lcm[512 + tid], Lcm[768 + tid]));
    colmax[n] = cm;
    float bv = -INFINITY;
    int br = -1;
#pragma unroll
    for (int w2 = 0; w2 < 4; ++w2) {
      float b = Lbv[w2 * 256 + tid];
      if (b > bv) { bv = b; br = Lbr[w2 * 256 + tid]; }
    }
    colargmax[n] = br;
  }

  double d1 = (double)s1, d2 = (double)s2;
#pragma unroll
  for (int o = 32; o > 0; o >>= 1) {
    d1 += __shfl_down(d1, o);
    d2 += __shfl_down(d2, o);
  }
  if ((tid & 63) == 0) { red[ty * 2] = d1; red[ty * 2 + 1] = d2; }
  __syncthreads();
  if (tid == 0) {
    atomicAdd(&sums[0], red[0] + red[2] + red[4] + red[6]);
    atomicAdd(&sums[1], red[1] + red[3] + red[5] + red[7]);
  }
}

// ---------- K4: fused column pass: collse + row exp-sums + candidate scatter ----------
// Replaces round-4's k_rowsum (52 MB re-read) + k_colstats. Candidates carry
// raw score x; prob is computed in k_topk (identical formula, rowstats ready).

__global__ __launch_bounds__(256) void k_colpass(const float* __restrict__ scores,
                                                 const float* __restrict__ colmax,
                                                 const int* __restrict__ colargmax,
                                                 const unsigned long long* __restrict__ mbits,
                                                 const double* __restrict__ sums,
                                                 const unsigned* __restrict__ rowmax_u,
                                                 float* __restrict__ collse,
                                                 float* __restrict__ rowacc,
                                                 int* __restrict__ cnt,
                                                 float* __restrict__ candx,
                                                 int* __restrict__ candn,
                                                 int N) {
  __shared__ float rmS[64], rmmS[64];
  __shared__ float rpu[64 * 4], rpm[64 * 4];
  __shared__ int lcnt[64], lbase[64];
  const int tid = threadIdx.x, lane = tid & 63, ty = tid >> 6;
  if (tid < 64) {
    rmS[tid] = funmap(rowmax_u[tid]);
    rmmS[tid] = funmap(rowmax_u[64 + tid]);
    lcnt[tid] = 0;
  }
  __syncthreads();
  const int n = blockIdx.x * 256 + tid;
  const bool valid = n < N;
  float fmu, istd;
  get_mu_istd(sums, N, fmu, istd);
  const float cm = valid ? colmax[n] : 0.f;
  const int br = valid ? colargmax[n] : -1;
  const unsigned long long mbn = valid ? mbits[n] : 0ull;
  float colsum = 0.f, xbr = 0.f;

  for (int r = 0; r < RR; ++r) {
    float x = valid ? scores[(size_t)r * N + n] : 0.f;
    if (r == br) xbr = x;
    if (valid) colsum += expf((x - cm) * istd);
    float eu = valid ? expf((x - rmS[r]) * istd) : 0.f;
    float em = (valid && ((mbn >> r) & 1ull)) ? expf((x - rmmS[r]) * istd) : 0.f;
#pragma unroll
    for (int o = 32; o > 0; o >>= 1) {
      eu += __shfl_down(eu, o);
      em += __shfl_down(em, o);
    }
    if (lane == 0) { rpu[r * 4 + ty] = eu; rpm[r * 4 + ty] = em; }
  }

  if (valid) collse[n] = logf(colsum);
  int lpos = 0;
  if (br >= 0) lpos = atomicAdd(&lcnt[br], 1);
  __syncthreads();
  if (tid < 64) {
    float su = rpu[tid * 4] + rpu[tid * 4 + 1] + rpu[tid * 4 + 2] + rpu[tid * 4 + 3];
    float sm = rpm[tid * 4] + rpm[tid * 4 + 1] + rpm[tid * 4 + 2] + rpm[tid * 4 + 3];
    atomicAdd(&rowacc[tid], su);
    atomicAdd(&rowacc[64 + tid], sm);
    int c = lcnt[tid];
    lbase[tid] = c ? atomicAdd(&cnt[tid], c) : 0;
  }
  __syncthreads();
  if (br >= 0) {
    int pos = lbase[br] + lpos;
    if (pos < CAP) {
      candx[(size_t)br * CAP + pos] = xbr;
      candn[(size_t)br * CAP + pos] = n;
    }
  }
}

// ---------- K3b: finalize row stats ----------
// rowstats: [r]=rowmax raw, [64+r]=log sumexp unmasked, [128+r]=masked rowmax raw, [192+r]=masked sumexp

__global__ void k_rowfin(const float* __restrict__ rowacc,
                         const unsigned* __restrict__ rowmax_u,
                         float* __restrict__ rowstats) {
  int r = threadIdx.x;  // 64
  rowstats[r] = funmap(rowmax_u[r]);
  rowstats[64 + r] = logf(rowacc[r]);
  rowstats[128 + r] = funmap(rowmax_u[64 + r]);
  rowstats[192 + r] = rowacc[64 + r];
}

// ---------- K5: per-row top-50 (prob desc, index asc), 512 threads ----------

__global__ __launch_bounds__(512) void k_topk(const int* __restrict__ cnt,
                                              const float* __restrict__ candx,
                                              const int* __restrict__ candn,
                                              const double* __restrict__ sums,
                                              const float* __restrict__ rowstats,
                                              float* __restrict__ out,
                                              int* __restrict__ seln,
                                              int N, int NO) {
  int r = blockIdx.x, tid = threadIdx.x;
  __shared__ float sp[CAP];
  __shared__ int sn[CAP];
  __shared__ float wp[8];
  __shared__ int wn[8], wi[8];
  int c = min(cnt[r], CAP);
  float fmu, istd;
  get_mu_istd(sums, N, fmu, istd);
  const float rmm = rowstats[128 + r];
  const float lm = rowstats[192 + r];
  for (int i = tid; i < c; i += 512) {
    float xv = candx[(size_t)r * CAP + i];
    sp[i] = fmaxf(expf((xv - rmm) * istd) / lm, 1e-6f);
    sn[i] = candn[(size_t)r * CAP + i];
  }
  __syncthreads();
  for (int j = 0; j < NO; ++j) {
    float bp = -1.f;
    int bn = 0x7fffffff, bi = -1;
    for (int i = tid; i < c; i += 512) {
      float p = sp[i];
      int nn = sn[i];
      if (p > bp || (p == bp && nn < bn)) { bp = p; bn = nn; bi = i; }
    }
#pragma unroll
    for (int o = 32; o > 0; o >>= 1) {
      float p2 = __shfl_down(bp, o);
      int n2 = __shfl_down(bn, o);
      int i2 = __shfl_down(bi, o);
      if (p2 > bp || (p2 == bp && n2 < bn)) { bp = p2; bn = n2; bi = i2; }
    }
    if ((tid & 63) == 0) { wp[tid >> 6] = bp; wn[tid >> 6] = bn; wi[tid >> 6] = bi; }
    __syncthreads();
    if (tid == 0) {
      float fp2 = wp[0]; int fn2 = wn[0], fi2 = wi[0];
#pragma unroll
      for (int w2 = 1; w2 < 8; ++w2) {
        if (wp[w2] > fp2 || (wp[w2] == fp2 && wn[w2] < fn2)) { fp2 = wp[w2]; fn2 = wn[w2]; fi2 = wi[w2]; }
      }
      if (fp2 > 0.f) {
        out[r * NO + j] = (float)fn2;
        seln[r * NO + j] = fn2;
        sp[fi2] = -1.f;
      } else {
        out[r * NO + j] = -1.f;
        seln[r * NO + j] = -1;
      }
    }
    __syncthreads();
  }
}

// ---------- K6: exp_scores ----------

__global__ void k_expand(const float* __restrict__ scores,
                         const double* __restrict__ sums,
                         const float* __restrict__ rowstats,
                         const float* __restrict__ colmax,
                         const float* __restrict__ collse,
                         const int* __restrict__ seln,
                         float* __restrict__ out,
                         int N, int NO) {
  int b = blockIdx.x;
  int r2 = threadIdx.x;
  int n = seln[b];
  float v = 0.f;
  if (n >= 0) {
    float fmu, istd;
    get_mu_istd(sums, N, fmu, istd);
    float x = scores[(size_t)r2 * N + n];
    float v1 = (x - rowstats[r2]) * istd - rowstats[64 + r2];
    float v2 = (x - colmax[n]) * istd - collse[n];
    v = v1 + v2;
  }
  out[RR * NO + (size_t)b * RR + r2] = v;
}

// ---------- launch ----------

extern "C" void kernel_launch(void* const* d_in, const int* in_sizes, int n_in,
                              void* d_out, int out_size, void* d_ws, size_t ws_size,
                              hipStream_t stream) {
  const float* hs = (const float*)d_in[0];
  const float* es = (const float*)d_in[1];
  const float* W = (const float*)d_in[2];
  const void* mask = d_in[3];

  const int N = in_sizes[1] / DD;               // 200000
  const int NO = out_size / (RR * (1 + RR));    // 50

  char* ws = (char*)d_ws;
  size_t o = 0;
  float* scores = (float*)(ws + o);   o += (size_t)RR * N * 4;
  float* hsW = (float*)(ws + o);      o += RR * DD * 4;
  o = (o + 255) & ~(size_t)255;
  // contiguous zero region: sums(16) + cnt(256) + rowmax_u(512) + rowacc(512)
  double* sums = (double*)(ws + o);
  int* cnt = (int*)(ws + o + 16);
  unsigned* rowmax_u = (unsigned*)(ws + o + 16 + 256);
  float* rowacc = (float*)(ws + o + 16 + 256 + 512);
  size_t zero_off = o, zero_bytes = 16 + 256 + 512 + 512;
  o += 1536;
  float* rowstats = (float*)(ws + o); o += 256 * 4;
  o = (o + 255) & ~(size_t)255;
  float* colmax = (float*)(ws + o);   o += (size_t)N * 4;
  int* colargmax = (int*)(ws + o);    o += (size_t)N * 4;
  float* collse = (float*)(ws + o);   o += (size_t)N * 4;
  o = (o + 255) & ~(size_t)255;
  unsigned long long* mbits = (unsigned long long*)(ws + o); o += (size_t)N * 8;
  o = (o + 255) & ~(size_t)255;
  float* candx = (float*)(ws + o);    o += (size_t)RR * CAP * 4;
  int* candn = (int*)(ws + o);        o += (size_t)RR * CAP * 4;
  int* seln = (int*)(ws + o);         o += (size_t)RR * NO * 4;

  hipMemsetAsync(ws + zero_off, 0, zero_bytes, stream);

  const int NB = (N + 255) / 256;

  k_mask<<<NB, 256, 0, stream>>>(mask, mbits, N);
  k_hsw<<<RR, 256, 0, stream>>>(hs, W, hsW);
  k_scores<<<NB, 256, 0, stream>>>(es, hsW, mbits, scores, colmax, colargmax, sums,
                                   rowmax_u, N);
  k_colpass<<<NB, 256, 0, stream>>>(scores, colmax, colargmax, mbits, sums, rowmax_u,
                                    collse, rowacc, cnt, candx, candn, N);
  k_rowfin<<<1, 64, 0, stream>>>(rowacc, rowmax_u, rowstats);
  k_topk<<<RR, 512, 0, stream>>>(cnt, candx, candn, sums, rowstats, (float*)d_out, seln,
                                 N, NO);
  k_expand<<<RR * NO, 64, 0, stream>>>(scores, sums, rowstats, colmax, collse, seln,
                                       (float*)d_out, N, NO);
}